// Round 1
// baseline (98.371 us; speedup 1.0000x reference)
//
#include <hip/hip_runtime.h>

#define NB   64
#define IN   512
#define OUT  512
#define NTOK 512      // B*T
#define K    2
#define NSEL (NTOK*K) // 1024
#define TC   16
#define OTILE 128

// Pass 1: build CSR lists of selection-indices per bank. Single block.
__global__ __launch_bounds__(1024) void build_lists(const int* __restrict__ sel,
                                                    int* __restrict__ counts,
                                                    int* __restrict__ offsets,
                                                    int* __restrict__ list) {
    __shared__ int lcnt[NB];
    __shared__ int loff[NB];
    const int t = threadIdx.x;
    if (t < NB) lcnt[t] = 0;
    __syncthreads();
    const int bank = sel[t];
    atomicAdd(&lcnt[bank], 1);
    __syncthreads();
    if (t == 0) {
        int run = 0;
        for (int b = 0; b < NB; ++b) { loff[b] = run; run += lcnt[b]; }
    }
    __syncthreads();
    if (t < NB) { counts[t] = lcnt[t]; offsets[t] = loff[t]; lcnt[t] = 0; }
    __syncthreads();
    const int pos = loff[bank] + atomicAdd(&lcnt[bank], 1);
    list[pos] = t;
}

// Pass 2: one block per (bank, out-tile). Stream W[bank][:, tile] once per
// 16-token chunk; x rows staged in LDS pre-scaled by prob.
__global__ __launch_bounds__(256) void banked_gemv(
    const float* __restrict__ x,      // [NTOK][IN]
    const float* __restrict__ probs,  // [NSEL]
    const float* __restrict__ W,      // [NB][IN][OUT]
    const float* __restrict__ bias,   // [NB][OUT]
    const int* __restrict__ counts,
    const int* __restrict__ offsets,
    const int* __restrict__ list,
    float* __restrict__ out)          // [NTOK][OUT]
{
    __shared__ float xs[TC][IN];      // 32 KB
    __shared__ int   tok_s[TC];
    __shared__ float prob_s[TC];

    const int bank  = blockIdx.x >> 2;
    const int otile = blockIdx.x & 3;
    const int n     = counts[bank];
    if (n == 0) return;
    const int start = offsets[bank];

    const int t   = threadIdx.x;
    const int ct  = t & (OTILE - 1);   // 0..127
    const int rg  = t >> 7;            // 0..1 (token row group)
    const int col = otile * OTILE + ct;

    const float* wcol  = W + ((size_t)bank * IN * OUT) + col;
    const float bias_v = bias[bank * OUT + col];

    for (int c0 = 0; c0 < n; c0 += TC) {
        if (t < TC) {
            const int idx = c0 + t;
            const int e = (idx < n) ? list[start + idx] : -1;
            tok_s[t]  = (e >= 0) ? (e >> 1) : 0;   // selection idx -> token
            prob_s[t] = (e >= 0) ? probs[e] : 0.0f;
        }
        __syncthreads();
        // cooperative stage: 16 rows x 128 float4, scaled by prob
        for (int idx = t; idx < TC * (IN / 4); idx += 256) {
            const int row = idx >> 7;
            const int c4  = idx & 127;
            float4 v = reinterpret_cast<const float4*>(x + (size_t)tok_s[row] * IN)[c4];
            const float p = prob_s[row];
            v.x *= p; v.y *= p; v.z *= p; v.w *= p;
            reinterpret_cast<float4*>(&xs[row][0])[c4] = v;
        }
        __syncthreads();

        float acc[8];
        #pragma unroll
        for (int j = 0; j < 8; ++j) acc[j] = 0.f;

        #pragma unroll 1
        for (int i = 0; i < IN; i += 4) {
            float4 xv[8];
            #pragma unroll
            for (int j = 0; j < 8; ++j)
                xv[j] = *reinterpret_cast<const float4*>(&xs[rg * 8 + j][i]);
            #pragma unroll
            for (int ii = 0; ii < 4; ++ii) {
                const float w = wcol[(size_t)(i + ii) * OUT];
                #pragma unroll
                for (int j = 0; j < 8; ++j) {
                    const float xvv = (ii == 0) ? xv[j].x
                                    : (ii == 1) ? xv[j].y
                                    : (ii == 2) ? xv[j].z : xv[j].w;
                    acc[j] += xvv * w;
                }
            }
        }

        #pragma unroll
        for (int j = 0; j < 8; ++j) {
            const int r = rg * 8 + j;
            if (c0 + r < n) {
                const float val = acc[j] + prob_s[r] * bias_v;
                atomicAdd(&out[(size_t)tok_s[r] * OUT + col], val);
            }
        }
        __syncthreads();
    }
}

extern "C" void kernel_launch(void* const* d_in, const int* in_sizes, int n_in,
                              void* d_out, int out_size, void* d_ws, size_t ws_size,
                              hipStream_t stream) {
    const float* x     = (const float*)d_in[0];
    const int*   sel   = (const int*)d_in[1];
    const float* probs = (const float*)d_in[2];
    const float* W     = (const float*)d_in[3];
    const float* bias  = (const float*)d_in[4];
    float* out = (float*)d_out;

    int* counts  = (int*)d_ws;        // 64
    int* offsets = counts + NB;       // 64
    int* list    = offsets + NB;      // 1024  (total ~4.6 KB of d_ws)

    hipMemsetAsync(d_out, 0, (size_t)out_size * sizeof(float), stream);
    build_lists<<<1, NSEL, 0, stream>>>(sel, counts, offsets, list);
    banked_gemv<<<NB * 4, 256, 0, stream>>>(x, probs, W, bias, counts, offsets, list, out);
}